// Round 5
// baseline (370.493 us; speedup 1.0000x reference)
//
#include <hip/hip_runtime.h>
#include <cstddef>

#define NPB  4096            // points per batch
#define KNB  20              // neighbors
#define NB   8               // batches
#define NPTS (NB * NPB)      // 32768 total points

// ---------------------------------------------------------------------------
// Kernel A: pack (x,y,z,xx) per point into float4 (512 KB, L2-resident).
// xx arithmetic identical to reference numpy fp32 (no FMA, sequential order).
// ---------------------------------------------------------------------------
__global__ __launch_bounds__(256) void pack_kernel(const float* __restrict__ x,
                                                   float4* __restrict__ xp) {
    const int g = blockIdx.x * 256 + threadIdx.x;
    const int b = g >> 12, n = g & (NPB - 1);
    const float* xb = x + (size_t)b * 3 * NPB;
    float a0 = xb[n], a1 = xb[NPB + n], a2 = xb[2 * NPB + n];
    float xx = __fadd_rn(__fadd_rn(__fmul_rn(a0, a0), __fmul_rn(a1, a1)),
                         __fmul_rn(a2, a2));
    xp[g] = make_float4(a0, a1, a2, xx);
}

// ---------------------------------------------------------------------------
// Kernel P: fold BN into conv weights once.
// ---------------------------------------------------------------------------
__global__ __launch_bounds__(256) void prep_kernel(
    const float* __restrict__ w1, const float* __restrict__ b1,
    const float* __restrict__ g1, const float* __restrict__ be1,
    const float* __restrict__ rm1, const float* __restrict__ rv1,
    const float* __restrict__ w2, const float* __restrict__ b2,
    const float* __restrict__ g2, const float* __restrict__ be2,
    const float* __restrict__ rm2, const float* __restrict__ rv2,
    float* __restrict__ w1f, float* __restrict__ w2f, float* __restrict__ w2b)
{
    const int tid = threadIdx.x;
    if (tid < 64) {
        float sc1 = g1[tid] * rsqrtf(rv1[tid] + 1e-5f);
        float sh1 = be1[tid] - rm1[tid] * sc1;
#pragma unroll
        for (int j = 0; j < 6; ++j) w1f[tid * 8 + j] = sc1 * w1[tid * 6 + j];
        w1f[tid * 8 + 6] = sc1 * b1[tid] + sh1;
        w1f[tid * 8 + 7] = 0.f;
        float sc2 = g2[tid] * rsqrtf(rv2[tid] + 1e-5f);
        w2b[tid] = sc2 * b2[tid] + (be2[tid] - rm2[tid] * sc2);
    }
    for (int i = tid; i < 64 * 128; i += 256) {
        int c = i >> 6, o = i & 63;
        float sc2 = g2[o] * rsqrtf(rv2[o] + 1e-5f);
        w2f[i] = sc2 * w2[o * 128 + c];
    }
}

// ---------------------------------------------------------------------------
// Kernel B: exact top-20 SET per point (pooling is order-invariant, so only
// the set matters). Block = 64 points x 4 segment-waves (1024 cands each).
// Phase A: 20th-largest VALUE t via buffered value-only insertion (3-op
// steps) + racy cross-wave threshold sharing (any wave's 20th-so-far is a
// safe lower bound on the global 20th). In-block 4-way merge -> exact t.
// Phase B: rescan, collect {d >= t} survivors; wave0 assembles the reference
// set (d > t, then d == t lowest-index-first) and writes transposed knn_t.
// ---------------------------------------------------------------------------
union KSMem {
    struct {
        float buf[16][256];      // phase-A push buffers [slot][tid]
        float vals[4][20][64];   // phase-A partial value lists [wave][j][pt]
        float share[4][64];      // cross-wave vmin sharing [wave][pt]
    } a;
    struct {
        float2 list[4][64][20];  // phase-B survivors [wave][pt][j]
        int    cnt[4][64];
        int    out[20][64];      // final index staging [k][pt]
    } b;
};

__global__ __launch_bounds__(256) void knn_kernel(const float4* __restrict__ xp,
                                                  int* __restrict__ knn_t) {
    __shared__ KSMem sm;
    const int tid  = threadIdx.x;
    const int wv   = __builtin_amdgcn_readfirstlane(tid >> 6);
    const int lane = tid & 63;
    const int g0   = blockIdx.x * 64;
    const int b    = g0 >> 12;

    sm.a.share[wv][lane] = -INFINITY;
    __syncthreads();

    const float4 me = xp[g0 + lane];                 // coalesced
    const float cx = me.x, cy = me.y, cz = me.z, xxn = me.w;

    float vals[KNB];
#pragma unroll
    for (int j = 0; j < KNB; ++j) vals[j] = -INFINITY;
    float vmin = -INFINITY, thr = -INFINITY;
    int   cnt  = 0;

    auto flush = [&]() {
#pragma unroll
        for (int j = 0; j < 16; ++j) {
            if (!__any(j < cnt)) break;
            float cv = (j < cnt) ? sm.a.buf[j][tid] : -INFINITY;
            if (__any(cv > vmin)) {
#pragma unroll
                for (int q = 0; q < KNB; ++q) {      // value-only 3-op step
                    bool gt = cv > vals[q];
                    float tv = vals[q];
                    vals[q] = gt ? cv : tv;
                    cv      = gt ? tv : cv;
                }
                vmin = vals[KNB - 1];
            }
        }
        cnt = 0;
        if (vmin > thr) thr = vmin;
    };

    const float4* cand = xp + (b << 12) + wv * 1024; // uniform -> s_load
#pragma unroll 1
    for (int i = 0; i < 1024; i += 8) {
        if ((i & 63) == 0) {                         // racy share: stale = safe
            sm.a.share[wv][lane] = vmin;
            float t0 = sm.a.share[0][lane], t1 = sm.a.share[1][lane];
            float t2 = sm.a.share[2][lane], t3 = sm.a.share[3][lane];
            thr = fmaxf(fmaxf(t0, t1), fmaxf(t2, t3));
            if (vmin > thr) thr = vmin;
        }
#pragma unroll
        for (int u = 0; u < 8; ++u) {
            float4 q = cand[i + u];
            float inner = __fadd_rn(__fadd_rn(__fmul_rn(cx, q.x), __fmul_rn(cy, q.y)),
                                    __fmul_rn(cz, q.z));
            float d = __fsub_rn(__fsub_rn(__fmul_rn(2.0f, inner), xxn), q.w);
            if (d > thr) { sm.a.buf[cnt][tid] = d; ++cnt; }
        }
        if (__any(cnt >= 9)) flush();                // cap: 8 + 8 = 16 slots
    }
    flush();

#pragma unroll
    for (int j = 0; j < KNB; ++j) sm.a.vals[wv][j][lane] = vals[j];
    __syncthreads();

    // every wave redundantly merges the 4 sorted lists -> t (20th largest)
    float t = -INFINITY;
    {
        int p0 = 0, p1 = 0, p2 = 0, p3 = 0;
#pragma unroll 1
        for (int k = 0; k < KNB; ++k) {
            float e0 = sm.a.vals[0][p0][lane];
            float e1 = sm.a.vals[1][p1][lane];
            float e2 = sm.a.vals[2][p2][lane];
            float e3 = sm.a.vals[3][p3][lane];
            float bv = e0; int bs = 0;
            if (e1 > bv) { bv = e1; bs = 1; }
            if (e2 > bv) { bv = e2; bs = 2; }
            if (e3 > bv) { bv = e3; bs = 3; }
            t = bv;
            p0 += (bs == 0); p1 += (bs == 1); p2 += (bs == 2); p3 += (bs == 3);
        }
    }
    __syncthreads();                                 // retire phase-A smem

    // phase B: collect survivors d >= t
    int myc = 0;
#pragma unroll 1
    for (int i = 0; i < 1024; i += 8) {
#pragma unroll
        for (int u = 0; u < 8; ++u) {
            float4 q = cand[i + u];
            float inner = __fadd_rn(__fadd_rn(__fmul_rn(cx, q.x), __fmul_rn(cy, q.y)),
                                    __fmul_rn(cz, q.z));
            float d = __fsub_rn(__fsub_rn(__fmul_rn(2.0f, inner), xxn), q.w);
            if (d >= t) {
                if (myc < KNB)
                    sm.b.list[wv][lane][myc] =
                        make_float2(d, __int_as_float(wv * 1024 + i + u));
                ++myc;
            }
        }
    }
    sm.b.cnt[wv][lane] = (myc < KNB) ? myc : KNB;
    __syncthreads();

    if (wv == 0) {
        int cw0 = sm.b.cnt[0][lane], cw1 = sm.b.cnt[1][lane];
        int cw2 = sm.b.cnt[2][lane], cw3 = sm.b.cnt[3][lane];
        int nout = 0;
#pragma unroll 1
        for (int pass = 0; pass < 2; ++pass) {       // 0: d>t, 1: d==t
#pragma unroll 1
            for (int w = 0; w < 4; ++w) {
                int cw = (w == 0) ? cw0 : (w == 1) ? cw1 : (w == 2) ? cw2 : cw3;
#pragma unroll 1
                for (int j = 0; j < KNB; ++j) {
                    if (!__any(j < cw)) break;
                    if (j < cw) {
                        float2 e = sm.b.list[w][lane][j];
                        bool take = (pass == 0) ? (e.x > t) : (e.x == t);
                        if (take && nout < KNB) {
                            sm.b.out[nout][lane] = __float_as_int(e.y);
                            ++nout;
                        }
                    }
                }
            }
        }
#pragma unroll
        for (int k = 0; k < KNB; ++k)
            knn_t[k * NPTS + g0 + lane] = sm.b.out[k][lane];
    }
}

// ---------------------------------------------------------------------------
// Kernel C: fused gather + conv1+BN+ReLU + max/mean pool + conv2+BN+ReLU.
// Thread = point (lane = pt); wave owns a channel quarter. Wave id via
// readfirstlane so all weight addresses are provably uniform -> s_load.
// ---------------------------------------------------------------------------
__global__ __launch_bounds__(256) void fuse_kernel(
    const float4* __restrict__ xp, const int* __restrict__ knn_t,
    const float* __restrict__ w1f, const float* __restrict__ w2f,
    const float* __restrict__ w2b, float* __restrict__ out)
{
    __shared__ float cat[128 * 64];   // 32KB: [c][pt], c<64: m1, c>=64: m2

    const int tid  = threadIdx.x;
    const int wave = __builtin_amdgcn_readfirstlane(tid >> 6);
    const int lane = tid & 63;
    const int g0   = blockIdx.x * 64;
    const int b    = g0 >> 12, n0 = g0 & (NPB - 1);

    const float4 me = xp[g0 + lane];
    const float c0 = me.x, c1 = me.y, c2 = me.z;

    // gather 20 neighbor difs into registers (coalesced knn_t reads)
    int nidx[KNB];
#pragma unroll
    for (int k = 0; k < KNB; ++k) nidx[k] = knn_t[k * NPTS + g0 + lane];
    float dx[KNB], dy[KNB], dz[KNB];
#pragma unroll
    for (int k = 0; k < KNB; ++k) {
        float4 nb = xp[(b << 12) + nidx[k]];
        dx[k] = __fsub_rn(nb.x, c0);
        dy[k] = __fsub_rn(nb.y, c1);
        dz[k] = __fsub_rn(nb.z, c2);
    }

    // conv1 quarter: channels [16*wave, 16*wave+16)
    const float4* w1fv = (const float4*)w1f;
#pragma unroll 1
    for (int cc = 0; cc < 16; ++cc) {
        int c = wave * 16 + cc;                      // uniform -> s_load
        float4 wa = w1fv[c * 2];                     // {W0,W1,W2,W3}
        float4 wb = w1fv[c * 2 + 1];                 // {W4,W5,B1',pad}
        float base = wb.z + wa.w * c0 + wb.x * c1 + wb.y * c2;
        float m1 = -INFINITY, s = 0.f;
#pragma unroll
        for (int k = 0; k < KNB; ++k) {
            float h = fmaf(dz[k], wa.z, fmaf(dy[k], wa.y, fmaf(dx[k], wa.x, base)));
            float r = fmaxf(0.f, h);
            m1 = fmaxf(m1, r);
            s += r;
        }
        cat[c * 64 + lane]        = m1;
        cat[(64 + c) * 64 + lane] = s / 20.0f;
    }
    __syncthreads();

    const size_t SEC = (size_t)NB * 64 * NPB;   // elements per output section

    // write m1/m2 rows straight from cat (coalesced 256B rows)
#pragma unroll 1
    for (int q = 0; q < 32; ++q) {
        int r  = wave * 32 + q;                 // 0..127, uniform
        int ch = r & 63;
        float* dst = out + SEC * (1 + (r >> 6)) + ((size_t)b * 64 + ch) * NPB + n0;
        dst[lane] = cat[r * 64 + lane];
    }

    // conv2 quarter: outputs [16*wave, 16*wave+16)
    const int ob = wave * 16;                    // uniform -> s_load weights
    float acc[16];
#pragma unroll
    for (int j = 0; j < 16; ++j) acc[j] = w2b[ob + j];
#pragma unroll 4
    for (int c = 0; c < 128; ++c) {
        float v = cat[c * 64 + lane];
        const float4* wr = (const float4*)(w2f + c * 64 + ob);
        float4 q0 = wr[0], q1 = wr[1], q2 = wr[2], q3 = wr[3];
        acc[0]  = fmaf(v, q0.x, acc[0]);  acc[1]  = fmaf(v, q0.y, acc[1]);
        acc[2]  = fmaf(v, q0.z, acc[2]);  acc[3]  = fmaf(v, q0.w, acc[3]);
        acc[4]  = fmaf(v, q1.x, acc[4]);  acc[5]  = fmaf(v, q1.y, acc[5]);
        acc[6]  = fmaf(v, q1.z, acc[6]);  acc[7]  = fmaf(v, q1.w, acc[7]);
        acc[8]  = fmaf(v, q2.x, acc[8]);  acc[9]  = fmaf(v, q2.y, acc[9]);
        acc[10] = fmaf(v, q2.z, acc[10]); acc[11] = fmaf(v, q2.w, acc[11]);
        acc[12] = fmaf(v, q3.x, acc[12]); acc[13] = fmaf(v, q3.y, acc[13]);
        acc[14] = fmaf(v, q3.z, acc[14]); acc[15] = fmaf(v, q3.w, acc[15]);
    }
#pragma unroll
    for (int j = 0; j < 16; ++j) acc[j] = fmaxf(0.f, acc[j]);

    __syncthreads();                            // all waves done reading cat
#pragma unroll
    for (int j = 0; j < 16; ++j) cat[(ob + j) * 64 + lane] = acc[j];
    __syncthreads();
#pragma unroll 1
    for (int q = 0; q < 16; ++q) {
        int oo = wave * 16 + q;
        out[((size_t)b * 64 + oo) * NPB + n0 + lane] = cat[oo * 64 + lane];
    }
}

extern "C" void kernel_launch(void* const* d_in, const int* in_sizes, int n_in,
                              void* d_out, int out_size, void* d_ws, size_t ws_size,
                              hipStream_t stream) {
    const float* x   = (const float*)d_in[0];
    const float* w1  = (const float*)d_in[1];
    const float* b1  = (const float*)d_in[2];
    const float* g1  = (const float*)d_in[3];
    const float* be1 = (const float*)d_in[4];
    const float* rm1 = (const float*)d_in[5];
    const float* rv1 = (const float*)d_in[6];
    const float* w2  = (const float*)d_in[7];
    const float* b2  = (const float*)d_in[8];
    const float* g2  = (const float*)d_in[9];
    const float* be2 = (const float*)d_in[10];
    const float* rm2 = (const float*)d_in[11];
    const float* rv2 = (const float*)d_in[12];

    char*   ws    = (char*)d_ws;
    float4* xp    = (float4*)ws;                                // 512 KB
    int*    knn_t = (int*)(ws + 512 * 1024);                    // 2.62 MB
    float*  w1f   = (float*)(ws + 512 * 1024 + (size_t)KNB * NPTS * 4);
    float*  w2f   = w1f + 64 * 8;
    float*  w2b   = w2f + 64 * 128;

    pack_kernel<<<NPTS / 256, 256, 0, stream>>>(x, xp);
    prep_kernel<<<1, 256, 0, stream>>>(w1, b1, g1, be1, rm1, rv1,
                                       w2, b2, g2, be2, rm2, rv2, w1f, w2f, w2b);
    knn_kernel<<<NPTS / 64, 256, 0, stream>>>(xp, knn_t);
    fuse_kernel<<<NPTS / 64, 256, 0, stream>>>(xp, knn_t, w1f, w2f, w2b,
                                               (float*)d_out);
}

// Round 6
// 309.887 us; speedup vs baseline: 1.1956x; 1.1956x over previous
//
#include <hip/hip_runtime.h>
#include <cstddef>

#define NPB  4096            // points per batch
#define KNB  20              // neighbors
#define NB   8               // batches
#define NPTS (NB * NPB)      // 32768 total points
#define NSEG 8               // segment-waves per knn block
#define SEGW 512             // candidates per segment

// ---------------------------------------------------------------------------
// Kernel A: pack (x,y,z,xx) per point into float4 (512 KB, L2-resident).
// xx arithmetic identical to reference numpy fp32 (no FMA, sequential order).
// ---------------------------------------------------------------------------
__global__ __launch_bounds__(256) void pack_kernel(const float* __restrict__ x,
                                                   float4* __restrict__ xp) {
    const int g = blockIdx.x * 256 + threadIdx.x;
    const int b = g >> 12, n = g & (NPB - 1);
    const float* xb = x + (size_t)b * 3 * NPB;
    float a0 = xb[n], a1 = xb[NPB + n], a2 = xb[2 * NPB + n];
    float xx = __fadd_rn(__fadd_rn(__fmul_rn(a0, a0), __fmul_rn(a1, a1)),
                         __fmul_rn(a2, a2));
    xp[g] = make_float4(a0, a1, a2, xx);
}

// ---------------------------------------------------------------------------
// Kernel P: fold BN into conv weights once.
// ---------------------------------------------------------------------------
__global__ __launch_bounds__(256) void prep_kernel(
    const float* __restrict__ w1, const float* __restrict__ b1,
    const float* __restrict__ g1, const float* __restrict__ be1,
    const float* __restrict__ rm1, const float* __restrict__ rv1,
    const float* __restrict__ w2, const float* __restrict__ b2,
    const float* __restrict__ g2, const float* __restrict__ be2,
    const float* __restrict__ rm2, const float* __restrict__ rv2,
    float* __restrict__ w1f, float* __restrict__ w2f, float* __restrict__ w2b)
{
    const int tid = threadIdx.x;
    if (tid < 64) {
        float sc1 = g1[tid] * rsqrtf(rv1[tid] + 1e-5f);
        float sh1 = be1[tid] - rm1[tid] * sc1;
#pragma unroll
        for (int j = 0; j < 6; ++j) w1f[tid * 8 + j] = sc1 * w1[tid * 6 + j];
        w1f[tid * 8 + 6] = sc1 * b1[tid] + sh1;
        w1f[tid * 8 + 7] = 0.f;
        float sc2 = g2[tid] * rsqrtf(rv2[tid] + 1e-5f);
        w2b[tid] = sc2 * b2[tid] + (be2[tid] - rm2[tid] * sc2);
    }
    for (int i = tid; i < 64 * 128; i += 256) {
        int c = i >> 6, o = i & 63;
        float sc2 = g2[o] * rsqrtf(rv2[o] + 1e-5f);
        w2f[i] = sc2 * w2[o * 128 + c];
    }
}

// ---------------------------------------------------------------------------
// Kernel B: exact top-20 SET per point (pooling is order-invariant).
// Block = 512 thr = 64 points x 8 segment-waves (512 cands each) -> 4096
// waves total (2 blocks/CU, 16 waves/CU). Phase A: 20th-largest VALUE t via
// buffered value-only insertion (2-op max/min steps) + racy cross-wave
// threshold sharing; redundant in-block 8-way merge -> exact t. Phase B:
// rescan, collect {d >= t} survivors (idx | strict-bit); wave0 assembles
// the reference set (d > t first, then d == t in segment/index order) and
// writes transposed knn_t. Identical numpy-style fp32 distance arithmetic.
// ---------------------------------------------------------------------------
union KSMem {
    struct {
        float buf[10][512];         // 20KB push buffers [slot][tid]
        float vals[NSEG][KNB][64];  // 40KB partial value lists [wave][j][pt]
        float share[NSEG][64];      // 2KB cross-wave vmin sharing
    } a;
    struct {
        int list[NSEG][64][21];     // 42KB survivors idx|(strict<<31), pad 21
        int cnt[NSEG][64];          // 2KB
        int out[KNB][64];           // 5KB final index staging [k][pt]
    } b;
};

__global__ __launch_bounds__(512, 4) void knn_kernel(const float4* __restrict__ xp,
                                                     int* __restrict__ knn_t) {
    __shared__ KSMem sm;
    const int tid  = threadIdx.x;
    const int wv   = __builtin_amdgcn_readfirstlane(tid >> 6);
    const int lane = tid & 63;
    const int g0   = blockIdx.x * 64;
    const int b    = g0 >> 12;

    sm.a.share[wv][lane] = -INFINITY;
    __syncthreads();

    const float4 me = xp[g0 + lane];                 // coalesced
    const float cx = me.x, cy = me.y, cz = me.z, xxn = me.w;

    float vals[KNB];
#pragma unroll
    for (int j = 0; j < KNB; ++j) vals[j] = -INFINITY;
    float vmin = -INFINITY, thr = -INFINITY;
    int   cnt  = 0;

    auto flush = [&]() {
#pragma unroll
        for (int j = 0; j < 10; ++j) {
            if (!__any(j < cnt)) break;
            float cv = (j < cnt) ? sm.a.buf[j][tid] : -INFINITY;
            if (__any(cv > vmin)) {
#pragma unroll
                for (int q = 0; q < KNB; ++q) {      // 2-op step: max/min
                    float nv = fmaxf(cv, vals[q]);
                    cv       = fminf(cv, vals[q]);
                    vals[q]  = nv;
                }
                vmin = vals[KNB - 1];
            }
        }
        cnt = 0;
        if (vmin > thr) thr = vmin;
    };

    const float4* cand = xp + (b << 12) + wv * SEGW; // uniform -> s_load
#pragma unroll 1
    for (int i = 0; i < SEGW; i += 4) {
        if ((i & 63) == 0) {                         // racy share: stale = safe
            sm.a.share[wv][lane] = vmin;
            float mx = -INFINITY;
#pragma unroll
            for (int w = 0; w < NSEG; ++w) mx = fmaxf(mx, sm.a.share[w][lane]);
            thr = fmaxf(thr, mx);
        }
#pragma unroll
        for (int u = 0; u < 4; ++u) {
            float4 q = cand[i + u];
            float inner = __fadd_rn(__fadd_rn(__fmul_rn(cx, q.x), __fmul_rn(cy, q.y)),
                                    __fmul_rn(cz, q.z));
            float d = __fsub_rn(__fsub_rn(__fmul_rn(2.0f, inner), xxn), q.w);
            if (d > thr) { sm.a.buf[cnt][tid] = d; ++cnt; }
        }
        if (__any(cnt >= 7)) flush();                // cap: 6 + 4 = 10 slots
    }
    flush();

#pragma unroll
    for (int j = 0; j < KNB; ++j) sm.a.vals[wv][j][lane] = vals[j];
    __syncthreads();

    // every wave redundantly merges the 8 sorted value lists -> t (20th)
    float t = -INFINITY;
    {
        int p0 = 0, p1 = 0, p2 = 0, p3 = 0, p4 = 0, p5 = 0, p6 = 0, p7 = 0;
#pragma unroll 1
        for (int k = 0; k < KNB; ++k) {
            float e0 = sm.a.vals[0][p0][lane], e1 = sm.a.vals[1][p1][lane];
            float e2 = sm.a.vals[2][p2][lane], e3 = sm.a.vals[3][p3][lane];
            float e4 = sm.a.vals[4][p4][lane], e5 = sm.a.vals[5][p5][lane];
            float e6 = sm.a.vals[6][p6][lane], e7 = sm.a.vals[7][p7][lane];
            float bv = e0; int bs = 0;
            if (e1 > bv) { bv = e1; bs = 1; }
            if (e2 > bv) { bv = e2; bs = 2; }
            if (e3 > bv) { bv = e3; bs = 3; }
            if (e4 > bv) { bv = e4; bs = 4; }
            if (e5 > bv) { bv = e5; bs = 5; }
            if (e6 > bv) { bv = e6; bs = 6; }
            if (e7 > bv) { bv = e7; bs = 7; }
            t = bv;
            p0 += (bs == 0); p1 += (bs == 1); p2 += (bs == 2); p3 += (bs == 3);
            p4 += (bs == 4); p5 += (bs == 5); p6 += (bs == 6); p7 += (bs == 7);
        }
    }
    __syncthreads();                                 // retire phase-A smem

    // phase B: collect survivors d >= t (idx | strict-bit)
    int myc = 0;
#pragma unroll 1
    for (int i = 0; i < SEGW; i += 8) {
#pragma unroll
        for (int u = 0; u < 8; ++u) {
            float4 q = cand[i + u];
            float inner = __fadd_rn(__fadd_rn(__fmul_rn(cx, q.x), __fmul_rn(cy, q.y)),
                                    __fmul_rn(cz, q.z));
            float d = __fsub_rn(__fsub_rn(__fmul_rn(2.0f, inner), xxn), q.w);
            if (d >= t) {
                if (myc < KNB)
                    sm.b.list[wv][lane][myc] =
                        (wv * SEGW + i + u) | ((d > t) ? (int)0x80000000 : 0);
                ++myc;
            }
        }
    }
    sm.b.cnt[wv][lane] = (myc < KNB) ? myc : KNB;
    __syncthreads();

    if (wv == 0) {
        int nout = 0;
#pragma unroll 1
        for (int pass = 0; pass < 2; ++pass) {       // 0: d>t, 1: d==t
#pragma unroll 1
            for (int w = 0; w < NSEG; ++w) {
                int cw = sm.b.cnt[w][lane];
#pragma unroll 1
                for (int j = 0; j < KNB; ++j) {
                    if (!__any(j < cw)) break;
                    if (j < cw) {
                        int e = sm.b.list[w][lane][j];
                        bool strict = (e < 0);
                        bool take = (pass == 0) ? strict : !strict;
                        if (take && nout < KNB) {
                            sm.b.out[nout][lane] = e & 0x7fffffff;
                            ++nout;
                        }
                    }
                }
            }
        }
#pragma unroll
        for (int k = 0; k < KNB; ++k)
            knn_t[k * NPTS + g0 + lane] = sm.b.out[k][lane];
    }
}

// ---------------------------------------------------------------------------
// Kernel C: fused gather + conv1+BN+ReLU + max/mean pool + conv2+BN+ReLU.
// Block = 512 thr = 64 points x 8 channel-eighth waves (lane = point).
// Neighbor difs staged once in LDS by all 512 threads (2.5 scattered loads
// each, no per-thread redundancy), then read to registers. All weight
// addresses wave-uniform -> s_load. 47KB LDS, 16 waves/CU.
// ---------------------------------------------------------------------------
__global__ __launch_bounds__(512, 4) void fuse_kernel(
    const float4* __restrict__ xp, const int* __restrict__ knn_t,
    const float* __restrict__ w1f, const float* __restrict__ w2f,
    const float* __restrict__ w2b, float* __restrict__ out)
{
    __shared__ float cat[128 * 64];     // 32KB: [c][pt], c<64: m1, c>=64: m2
    __shared__ float dif[KNB][3][64];   // 15KB: [k][coord][pt]

    const int tid  = threadIdx.x;
    const int wave = __builtin_amdgcn_readfirstlane(tid >> 6);
    const int lane = tid & 63;
    const int g0   = blockIdx.x * 64;
    const int b    = g0 >> 12, n0 = g0 & (NPB - 1);

    // stage all 1280 (k,pt) neighbor difs cooperatively
#pragma unroll
    for (int r = 0; r < 3; ++r) {
        int p = tid + r * 512;
        if (p < KNB * 64) {
            int k = p >> 6, pt = p & 63;
            int nb = knn_t[k * NPTS + g0 + pt];          // coalesced
            float4 nq = xp[(b << 12) + nb];              // scattered (spread)
            float4 cq = xp[g0 + pt];                     // L1-hot
            dif[k][0][pt] = __fsub_rn(nq.x, cq.x);
            dif[k][1][pt] = __fsub_rn(nq.y, cq.y);
            dif[k][2][pt] = __fsub_rn(nq.z, cq.z);
        }
    }
    __syncthreads();

    const float4 me = xp[g0 + lane];
    const float c0 = me.x, c1 = me.y, c2 = me.z;
    float dx[KNB], dy[KNB], dz[KNB];
#pragma unroll
    for (int k = 0; k < KNB; ++k) {                      // conflict-free LDS
        dx[k] = dif[k][0][lane];
        dy[k] = dif[k][1][lane];
        dz[k] = dif[k][2][lane];
    }

    // conv1 eighth: channels [8*wave, 8*wave+8)
    const float4* w1fv = (const float4*)w1f;
#pragma unroll 1
    for (int cc = 0; cc < 8; ++cc) {
        int c = wave * 8 + cc;                           // uniform -> s_load
        float4 wa = w1fv[c * 2];                         // {W0,W1,W2,W3}
        float4 wb = w1fv[c * 2 + 1];                     // {W4,W5,B1',pad}
        float base = wb.z + wa.w * c0 + wb.x * c1 + wb.y * c2;
        float m1 = -INFINITY, s = 0.f;
#pragma unroll
        for (int k = 0; k < KNB; ++k) {
            float h = fmaf(dz[k], wa.z, fmaf(dy[k], wa.y, fmaf(dx[k], wa.x, base)));
            float r = fmaxf(0.f, h);
            m1 = fmaxf(m1, r);
            s += r;
        }
        cat[c * 64 + lane]        = m1;
        cat[(64 + c) * 64 + lane] = s / 20.0f;
    }
    __syncthreads();

    const size_t SEC = (size_t)NB * 64 * NPB;   // elements per output section

    // write m1/m2 rows straight from cat (coalesced 256B rows)
#pragma unroll 1
    for (int q = 0; q < 16; ++q) {
        int r  = wave * 16 + q;                 // 0..127, uniform
        int ch = r & 63;
        float* dst = out + SEC * (1 + (r >> 6)) + ((size_t)b * 64 + ch) * NPB + n0;
        dst[lane] = cat[r * 64 + lane];
    }

    // conv2 eighth: outputs [8*wave, 8*wave+8)
    const int ob = wave * 8;                    // uniform -> s_load weights
    float acc[8];
#pragma unroll
    for (int j = 0; j < 8; ++j) acc[j] = w2b[ob + j];
#pragma unroll 4
    for (int c = 0; c < 128; ++c) {
        float v = cat[c * 64 + lane];
        const float4* wr = (const float4*)(w2f + c * 64 + ob);
        float4 q0 = wr[0], q1 = wr[1];
        acc[0] = fmaf(v, q0.x, acc[0]);  acc[1] = fmaf(v, q0.y, acc[1]);
        acc[2] = fmaf(v, q0.z, acc[2]);  acc[3] = fmaf(v, q0.w, acc[3]);
        acc[4] = fmaf(v, q1.x, acc[4]);  acc[5] = fmaf(v, q1.y, acc[5]);
        acc[6] = fmaf(v, q1.z, acc[6]);  acc[7] = fmaf(v, q1.w, acc[7]);
    }
#pragma unroll
    for (int j = 0; j < 8; ++j) acc[j] = fmaxf(0.f, acc[j]);

    __syncthreads();                            // all waves done reading cat
#pragma unroll
    for (int j = 0; j < 8; ++j) cat[(ob + j) * 64 + lane] = acc[j];
    __syncthreads();
#pragma unroll 1
    for (int q = 0; q < 8; ++q) {
        int oo = wave * 8 + q;
        out[((size_t)b * 64 + oo) * NPB + n0 + lane] = cat[oo * 64 + lane];
    }
}

extern "C" void kernel_launch(void* const* d_in, const int* in_sizes, int n_in,
                              void* d_out, int out_size, void* d_ws, size_t ws_size,
                              hipStream_t stream) {
    const float* x   = (const float*)d_in[0];
    const float* w1  = (const float*)d_in[1];
    const float* b1  = (const float*)d_in[2];
    const float* g1  = (const float*)d_in[3];
    const float* be1 = (const float*)d_in[4];
    const float* rm1 = (const float*)d_in[5];
    const float* rv1 = (const float*)d_in[6];
    const float* w2  = (const float*)d_in[7];
    const float* b2  = (const float*)d_in[8];
    const float* g2  = (const float*)d_in[9];
    const float* be2 = (const float*)d_in[10];
    const float* rm2 = (const float*)d_in[11];
    const float* rv2 = (const float*)d_in[12];

    char*   ws    = (char*)d_ws;
    float4* xp    = (float4*)ws;                                // 512 KB
    int*    knn_t = (int*)(ws + 512 * 1024);                    // 2.62 MB
    float*  w1f   = (float*)(ws + 512 * 1024 + (size_t)KNB * NPTS * 4);
    float*  w2f   = w1f + 64 * 8;
    float*  w2b   = w2f + 64 * 128;

    pack_kernel<<<NPTS / 256, 256, 0, stream>>>(x, xp);
    prep_kernel<<<1, 256, 0, stream>>>(w1, b1, g1, be1, rm1, rv1,
                                       w2, b2, g2, be2, rm2, rv2, w1f, w2f, w2b);
    knn_kernel<<<NPTS / 64, 512, 0, stream>>>(xp, knn_t);
    fuse_kernel<<<NPTS / 64, 512, 0, stream>>>(xp, knn_t, w1f, w2f, w2b,
                                               (float*)d_out);
}

// Round 7
// 303.341 us; speedup vs baseline: 1.2214x; 1.0216x over previous
//
#include <hip/hip_runtime.h>
#include <cstddef>

#define NPB  4096            // points per batch
#define KNB  20              // neighbors
#define NB   8               // batches
#define NPTS (NB * NPB)      // 32768 total points
#define NSEG 8               // segment-waves per knn block
#define SEGW 512             // candidates per segment
#define NSLOT 12             // push-buffer slots per thread

// ---------------------------------------------------------------------------
// Kernel A: pack (x,y,z,xx) per point into float4 (512 KB, L2-resident).
// xx arithmetic identical to reference numpy fp32 (no FMA, sequential order).
// ---------------------------------------------------------------------------
__global__ __launch_bounds__(256) void pack_kernel(const float* __restrict__ x,
                                                   float4* __restrict__ xp) {
    const int g = blockIdx.x * 256 + threadIdx.x;
    const int b = g >> 12, n = g & (NPB - 1);
    const float* xb = x + (size_t)b * 3 * NPB;
    float a0 = xb[n], a1 = xb[NPB + n], a2 = xb[2 * NPB + n];
    float xx = __fadd_rn(__fadd_rn(__fmul_rn(a0, a0), __fmul_rn(a1, a1)),
                         __fmul_rn(a2, a2));
    xp[g] = make_float4(a0, a1, a2, xx);
}

// ---------------------------------------------------------------------------
// Kernel P: fold BN into conv weights once.
// ---------------------------------------------------------------------------
__global__ __launch_bounds__(256) void prep_kernel(
    const float* __restrict__ w1, const float* __restrict__ b1,
    const float* __restrict__ g1, const float* __restrict__ be1,
    const float* __restrict__ rm1, const float* __restrict__ rv1,
    const float* __restrict__ w2, const float* __restrict__ b2,
    const float* __restrict__ g2, const float* __restrict__ be2,
    const float* __restrict__ rm2, const float* __restrict__ rv2,
    float* __restrict__ w1f, float* __restrict__ w2f, float* __restrict__ w2b)
{
    const int tid = threadIdx.x;
    if (tid < 64) {
        float sc1 = g1[tid] * rsqrtf(rv1[tid] + 1e-5f);
        float sh1 = be1[tid] - rm1[tid] * sc1;
#pragma unroll
        for (int j = 0; j < 6; ++j) w1f[tid * 8 + j] = sc1 * w1[tid * 6 + j];
        w1f[tid * 8 + 6] = sc1 * b1[tid] + sh1;
        w1f[tid * 8 + 7] = 0.f;
        float sc2 = g2[tid] * rsqrtf(rv2[tid] + 1e-5f);
        w2b[tid] = sc2 * b2[tid] + (be2[tid] - rm2[tid] * sc2);
    }
    for (int i = tid; i < 64 * 128; i += 256) {
        int c = i >> 6, o = i & 63;
        float sc2 = g2[o] * rsqrtf(rv2[o] + 1e-5f);
        w2f[i] = sc2 * w2[o * 128 + c];
    }
}

// ---------------------------------------------------------------------------
// Kernel B: exact top-20 SET per point (pooling is order-invariant).
// Block = 512 thr = 64 points x 8 segment-waves (512 cands each).
// Phase A: 20th-largest VALUE t. Warm-up = direct sorted insert of first 20
// cands (vmin real immediately, no flush storm); then buffered value-only
// pushes (2-op max/min chain at flush) + racy cross-wave threshold sharing.
// In-block 8-way merge -> exact t. Phase B: rescan, collect {d >= t}
// survivors (idx | strict-bit); wave0 assembles the reference set (d > t
// first, then d == t in segment/index order) and writes transposed knn_t.
// LDS time-multiplexed union (51 KB) -> 3 blocks/CU.
// Identical numpy-style fp32 distance arithmetic throughout.
// ---------------------------------------------------------------------------
union KSMem {
    float buf[NSLOT][512];          // 24 KB scan push buffers [slot][tid]
    float vals[NSEG][KNB][64];      // 40 KB sorted partial lists [wave][j][pt]
    struct {
        int list[NSEG][64][21];     // 42 KB survivors idx|(strict<<31)
        int cnt[NSEG][64];          //  2 KB
        int out[KNB][64];           //  5 KB final index staging [k][pt]
    } b;                            // 49 KB
};

__global__ __launch_bounds__(512, 4) void knn_kernel(const float4* __restrict__ xp,
                                                     int* __restrict__ knn_t) {
    __shared__ KSMem sm;
    __shared__ float share[NSEG][64];   // cross-wave vmin, lives through scan

    const int tid  = threadIdx.x;
    const int wv   = __builtin_amdgcn_readfirstlane(tid >> 6);
    const int lane = tid & 63;
    const int g0   = blockIdx.x * 64;
    const int b    = g0 >> 12;

    share[wv][lane] = -INFINITY;
    __syncthreads();

    const float4 me = xp[g0 + lane];                 // coalesced
    const float cx = me.x, cy = me.y, cz = me.z, xxn = me.w;

    auto dist = [&](float4 q) -> float {
        float inner = __fadd_rn(__fadd_rn(__fmul_rn(cx, q.x), __fmul_rn(cy, q.y)),
                                __fmul_rn(cz, q.z));
        return __fsub_rn(__fsub_rn(__fmul_rn(2.0f, inner), xxn), q.w);
    };

    float vals[KNB];
#pragma unroll
    for (int j = 0; j < KNB; ++j) vals[j] = -INFINITY;

    const float4* cand = xp + (b << 12) + wv * SEGW;

    // warm-up: direct sorted insert of first 20 candidates (no buffering)
#pragma unroll 1
    for (int i = 0; i < KNB; ++i) {
        float cv = dist(cand[i]);
#pragma unroll
        for (int j = 0; j < KNB; ++j) {
            float nv = fmaxf(cv, vals[j]);
            cv       = fminf(cv, vals[j]);
            vals[j]  = nv;
        }
    }
    float vmin = vals[KNB - 1];
    float thr  = vmin;
    int   cnt  = 0;

    auto flush = [&]() {
#pragma unroll
        for (int j = 0; j < NSLOT; ++j) {
            if (!__any(j < cnt)) break;
            float cv = (j < cnt) ? sm.buf[j][tid] : -INFINITY;
#pragma unroll
            for (int q = 0; q < KNB; ++q) {          // 2-op step: max/min
                float nv = fmaxf(cv, vals[q]);
                cv       = fminf(cv, vals[q]);
                vals[q]  = nv;
            }
            vmin = vals[KNB - 1];
        }
        cnt = 0;
        thr = fmaxf(thr, vmin);
    };

    // remainder of first 64-cand chunk, buffered
#pragma unroll 1
    for (int i = KNB; i < 64; i += 4) {
#pragma unroll
        for (int u = 0; u < 4; ++u) {
            float d = dist(cand[i + u]);
            if (d > thr) { sm.buf[cnt][tid] = d; ++cnt; }
        }
        if (__any(cnt >= NSLOT - 3)) flush();        // 8 + 4 <= 12 slots
    }

    // main scan with cross-wave threshold refresh every 64 candidates
#pragma unroll 1
    for (int ii = 64; ii < SEGW; ii += 64) {
        share[wv][lane] = vmin;                      // racy: stale = safe
        float mx = share[0][lane];
#pragma unroll
        for (int w = 1; w < NSEG; ++w) mx = fmaxf(mx, share[w][lane]);
        thr = fmaxf(thr, mx);
#pragma unroll 1
        for (int i = ii; i < ii + 64; i += 4) {
#pragma unroll
            for (int u = 0; u < 4; ++u) {
                float d = dist(cand[i + u]);
                if (d > thr) { sm.buf[cnt][tid] = d; ++cnt; }
            }
            if (__any(cnt >= NSLOT - 3)) flush();
        }
    }
    flush();
    __syncthreads();                                 // retire push buffers

#pragma unroll
    for (int j = 0; j < KNB; ++j) sm.vals[wv][j][lane] = vals[j];
    __syncthreads();

    // every wave redundantly merges the 8 sorted value lists -> t (20th)
    float t = -INFINITY;
    {
        int p0 = 0, p1 = 0, p2 = 0, p3 = 0, p4 = 0, p5 = 0, p6 = 0, p7 = 0;
#pragma unroll 1
        for (int k = 0; k < KNB; ++k) {
            float e0 = sm.vals[0][p0][lane], e1 = sm.vals[1][p1][lane];
            float e2 = sm.vals[2][p2][lane], e3 = sm.vals[3][p3][lane];
            float e4 = sm.vals[4][p4][lane], e5 = sm.vals[5][p5][lane];
            float e6 = sm.vals[6][p6][lane], e7 = sm.vals[7][p7][lane];
            float bv = e0; int bs = 0;
            if (e1 > bv) { bv = e1; bs = 1; }
            if (e2 > bv) { bv = e2; bs = 2; }
            if (e3 > bv) { bv = e3; bs = 3; }
            if (e4 > bv) { bv = e4; bs = 4; }
            if (e5 > bv) { bv = e5; bs = 5; }
            if (e6 > bv) { bv = e6; bs = 6; }
            if (e7 > bv) { bv = e7; bs = 7; }
            t = bv;
            p0 += (bs == 0); p1 += (bs == 1); p2 += (bs == 2); p3 += (bs == 3);
            p4 += (bs == 4); p5 += (bs == 5); p6 += (bs == 6); p7 += (bs == 7);
        }
    }
    __syncthreads();                                 // retire vals (aliases b)

    // phase B: collect survivors d >= t (idx | strict-bit)
    int myc = 0;
#pragma unroll 1
    for (int i = 0; i < SEGW; i += 8) {
#pragma unroll
        for (int u = 0; u < 8; ++u) {
            float d = dist(cand[i + u]);
            if (d >= t) {
                if (myc < KNB)
                    sm.b.list[wv][lane][myc] =
                        (wv * SEGW + i + u) | ((d > t) ? (int)0x80000000 : 0);
                ++myc;
            }
        }
    }
    sm.b.cnt[wv][lane] = (myc < KNB) ? myc : KNB;
    __syncthreads();

    if (wv == 0) {
        int nout = 0;
#pragma unroll 1
        for (int pass = 0; pass < 2; ++pass) {       // 0: d>t, 1: d==t
#pragma unroll 1
            for (int w = 0; w < NSEG; ++w) {
                int cw = sm.b.cnt[w][lane];
#pragma unroll 1
                for (int j = 0; j < KNB; ++j) {
                    if (!__any(j < cw)) break;
                    if (j < cw) {
                        int e = sm.b.list[w][lane][j];
                        bool strict = (e < 0);
                        bool take = (pass == 0) ? strict : !strict;
                        if (take && nout < KNB) {
                            sm.b.out[nout][lane] = e & 0x7fffffff;
                            ++nout;
                        }
                    }
                }
            }
        }
#pragma unroll
        for (int k = 0; k < KNB; ++k)
            knn_t[k * NPTS + g0 + lane] = sm.b.out[k][lane];
    }
}

// ---------------------------------------------------------------------------
// Kernel C: fused gather + conv1+BN+ReLU + max/mean pool + conv2+BN+ReLU.
// Block = 512 thr = 64 points x 8 channel-eighth waves (lane = point).
// Neighbor difs staged once in LDS cooperatively; weights via uniform
// s_load. (unchanged from round 6 — validated)
// ---------------------------------------------------------------------------
__global__ __launch_bounds__(512, 4) void fuse_kernel(
    const float4* __restrict__ xp, const int* __restrict__ knn_t,
    const float* __restrict__ w1f, const float* __restrict__ w2f,
    const float* __restrict__ w2b, float* __restrict__ out)
{
    __shared__ float cat[128 * 64];     // 32KB: [c][pt], c<64: m1, c>=64: m2
    __shared__ float dif[KNB][3][64];   // 15KB: [k][coord][pt]

    const int tid  = threadIdx.x;
    const int wave = __builtin_amdgcn_readfirstlane(tid >> 6);
    const int lane = tid & 63;
    const int g0   = blockIdx.x * 64;
    const int b    = g0 >> 12, n0 = g0 & (NPB - 1);

    // stage all 1280 (k,pt) neighbor difs cooperatively
#pragma unroll
    for (int r = 0; r < 3; ++r) {
        int p = tid + r * 512;
        if (p < KNB * 64) {
            int k = p >> 6, pt = p & 63;
            int nb = knn_t[k * NPTS + g0 + pt];          // coalesced
            float4 nq = xp[(b << 12) + nb];              // scattered (spread)
            float4 cq = xp[g0 + pt];                     // L1-hot
            dif[k][0][pt] = __fsub_rn(nq.x, cq.x);
            dif[k][1][pt] = __fsub_rn(nq.y, cq.y);
            dif[k][2][pt] = __fsub_rn(nq.z, cq.z);
        }
    }
    __syncthreads();

    const float4 me = xp[g0 + lane];
    const float c0 = me.x, c1 = me.y, c2 = me.z;
    float dx[KNB], dy[KNB], dz[KNB];
#pragma unroll
    for (int k = 0; k < KNB; ++k) {                      // conflict-free LDS
        dx[k] = dif[k][0][lane];
        dy[k] = dif[k][1][lane];
        dz[k] = dif[k][2][lane];
    }

    // conv1 eighth: channels [8*wave, 8*wave+8)
    const float4* w1fv = (const float4*)w1f;
#pragma unroll 1
    for (int cc = 0; cc < 8; ++cc) {
        int c = wave * 8 + cc;                           // uniform -> s_load
        float4 wa = w1fv[c * 2];                         // {W0,W1,W2,W3}
        float4 wb = w1fv[c * 2 + 1];                     // {W4,W5,B1',pad}
        float base = wb.z + wa.w * c0 + wb.x * c1 + wb.y * c2;
        float m1 = -INFINITY, s = 0.f;
#pragma unroll
        for (int k = 0; k < KNB; ++k) {
            float h = fmaf(dz[k], wa.z, fmaf(dy[k], wa.y, fmaf(dx[k], wa.x, base)));
            float r = fmaxf(0.f, h);
            m1 = fmaxf(m1, r);
            s += r;
        }
        cat[c * 64 + lane]        = m1;
        cat[(64 + c) * 64 + lane] = s / 20.0f;
    }
    __syncthreads();

    const size_t SEC = (size_t)NB * 64 * NPB;   // elements per output section

    // write m1/m2 rows straight from cat (coalesced 256B rows)
#pragma unroll 1
    for (int q = 0; q < 16; ++q) {
        int r  = wave * 16 + q;                 // 0..127, uniform
        int ch = r & 63;
        float* dst = out + SEC * (1 + (r >> 6)) + ((size_t)b * 64 + ch) * NPB + n0;
        dst[lane] = cat[r * 64 + lane];
    }

    // conv2 eighth: outputs [8*wave, 8*wave+8)
    const int ob = wave * 8;                    // uniform -> s_load weights
    float acc[8];
#pragma unroll
    for (int j = 0; j < 8; ++j) acc[j] = w2b[ob + j];
#pragma unroll 4
    for (int c = 0; c < 128; ++c) {
        float v = cat[c * 64 + lane];
        const float4* wr = (const float4*)(w2f + c * 64 + ob);
        float4 q0 = wr[0], q1 = wr[1];
        acc[0] = fmaf(v, q0.x, acc[0]);  acc[1] = fmaf(v, q0.y, acc[1]);
        acc[2] = fmaf(v, q0.z, acc[2]);  acc[3] = fmaf(v, q0.w, acc[3]);
        acc[4] = fmaf(v, q1.x, acc[4]);  acc[5] = fmaf(v, q1.y, acc[5]);
        acc[6] = fmaf(v, q1.z, acc[6]);  acc[7] = fmaf(v, q1.w, acc[7]);
    }
#pragma unroll
    for (int j = 0; j < 8; ++j) acc[j] = fmaxf(0.f, acc[j]);

    __syncthreads();                            // all waves done reading cat
#pragma unroll
    for (int j = 0; j < 8; ++j) cat[(ob + j) * 64 + lane] = acc[j];
    __syncthreads();
#pragma unroll 1
    for (int q = 0; q < 8; ++q) {
        int oo = wave * 8 + q;
        out[((size_t)b * 64 + oo) * NPB + n0 + lane] = cat[oo * 64 + lane];
    }
}

extern "C" void kernel_launch(void* const* d_in, const int* in_sizes, int n_in,
                              void* d_out, int out_size, void* d_ws, size_t ws_size,
                              hipStream_t stream) {
    const float* x   = (const float*)d_in[0];
    const float* w1  = (const float*)d_in[1];
    const float* b1  = (const float*)d_in[2];
    const float* g1  = (const float*)d_in[3];
    const float* be1 = (const float*)d_in[4];
    const float* rm1 = (const float*)d_in[5];
    const float* rv1 = (const float*)d_in[6];
    const float* w2  = (const float*)d_in[7];
    const float* b2  = (const float*)d_in[8];
    const float* g2  = (const float*)d_in[9];
    const float* be2 = (const float*)d_in[10];
    const float* rm2 = (const float*)d_in[11];
    const float* rv2 = (const float*)d_in[12];

    char*   ws    = (char*)d_ws;
    float4* xp    = (float4*)ws;                                // 512 KB
    int*    knn_t = (int*)(ws + 512 * 1024);                    // 2.62 MB
    float*  w1f   = (float*)(ws + 512 * 1024 + (size_t)KNB * NPTS * 4);
    float*  w2f   = w1f + 64 * 8;
    float*  w2b   = w2f + 64 * 128;

    pack_kernel<<<NPTS / 256, 256, 0, stream>>>(x, xp);
    prep_kernel<<<1, 256, 0, stream>>>(w1, b1, g1, be1, rm1, rv1,
                                       w2, b2, g2, be2, rm2, rv2, w1f, w2f, w2b);
    knn_kernel<<<NPTS / 64, 512, 0, stream>>>(xp, knn_t);
    fuse_kernel<<<NPTS / 64, 512, 0, stream>>>(xp, knn_t, w1f, w2f, w2b,
                                               (float*)d_out);
}